// Round 8
// baseline (4918.317 us; speedup 1.0000x reference)
//
#include <hip/hip_runtime.h>
#include <math.h>

// Problem constants (match reference)
#define B_   1024
#define NC   100
#define NN   101          // N = NC + 1
#define E_   128
#define T_   202          // 2*N
#define NEGV   -1.0e9
#define GAPTHR 4.0e-3f    // fp32-path error bound ~3e-4 -> 13x margin
#define INVSQE 0.08838834764831845f
#define INVSQED 0.08838834764831845

__device__ __forceinline__ float rdlane(float v, int l) {
    return __int_as_float(__builtin_amdgcn_readlane(__float_as_int(v), l));
}

// ---------------------------------------------------------------------------
// kernel 0: M = Wk2 @ Wout^T (128x128) into ws as fp64 (fallback) + fp32 (fast)
// ---------------------------------------------------------------------------
__global__ void k_weights(const float* __restrict__ Wk2,
                          const float* __restrict__ Wout,
                          double* __restrict__ M64,
                          float* __restrict__ M32) {
    int g = blockIdx.x;   // 0..127
    int e = threadIdx.x;  // 0..127
    const float* w2 = Wk2 + g * E_;
    const float* wo = Wout + e * E_;
    double acc = 0.0;
#pragma unroll 8
    for (int f = 0; f < E_; ++f) acc += (double)w2[f] * (double)wo[f];
    M64[g * E_ + e] = acc;
    M32[g * E_ + e] = (float)acc;
}

// ---------------------------------------------------------------------------
// Main decoder. 1 block / batch element, 512 threads (8 waves), 2 blocks/CU.
// LDS ~74 KB (sV + union scratch); Kstep rows in global ws (L2-resident).
// Register arrays capped at 64 floats/thread (rA[32]+rK2[32]) -> VGPR=128,
// which is exactly the 2-blocks/CU register budget (4 waves/SIMD x 128).
// 4 barriers/step. Exact fp64 fallback on near-tie argmax (gap < GAPTHR).
// ---------------------------------------------------------------------------
__global__ __launch_bounds__(512, 2)
void k_decode(const float* __restrict__ depot_xy,
              const float* __restrict__ customer_xy,
              const float* __restrict__ demand,
              const float* __restrict__ node_emb,
              const float* __restrict__ graph_emb,
              const float* __restrict__ Wk1,
              const float* __restrict__ Wv,
              const float* __restrict__ Wq_fixed,
              const float* __restrict__ Wq_step,
              const double* __restrict__ M64,
              const float* __restrict__ M32,
              float* __restrict__ gks,          // [B][101][128] Kstep, or null
              float* __restrict__ out)          // [2*B]: cost then ll
{
    __shared__ float  sV [NN * E_];             // 51.7 KB V rows fp32
    __shared__ double sU[2224];                 // union scratch 17.8 KB
    __shared__ double sQfix64[E_];
    __shared__ double sWqD64[E_];
    __shared__ float  sQfix32[E_];
    __shared__ float  sWqD32[E_];
    __shared__ float  sInvS[8];
    __shared__ float  sCoord[2 * NN];
    __shared__ float  sDem[NC];
    __shared__ float  sD;
    __shared__ double sCost, sLL;
    __shared__ float  sPosX, sPosY;
    __shared__ int    sPrev, sMaskDepot, sTrig, sOvf;
    __shared__ unsigned long long sVis0, sVis1;

    // fast fp32 views (overlay the fp64 fallback scratch)
    float* fSc   = (float*)sU;          // [8][104] exp-scores (pads 101..103)
    float* fPart = (float*)sU + 832;    // [4][128] glimpse partials
    float* fPx   = (float*)sU + 1344;   // [4][128] logit partials
    float* fQ1   = (float*)sU + 1856;   // [128] q1 (only used when !gks)
    // fallback fp64 views (not live at same time as fSc/fPart/fPx)
    double* dUZ = sU;                   // [128][8] u1 then z
    double* dSc = sU + 1024;            // [8][101] scores -> weights
    double* dQ1 = sU + 1832;            // [128] q1, later xd[101]
    double* dGl = sU + 1960;            // [128]
    double* dVg = sU + 2088;            // [128]

    const int b      = blockIdx.x;
    const int tid    = threadIdx.x;
    const int lane   = tid & 63;
    const int h      = __builtin_amdgcn_readfirstlane(tid >> 6);   // head 0..7
    const int k1     = lane + 64;                                  // 2nd node
    const int k_lane = tid & 127;
    const int q2u    = __builtin_amdgcn_readfirstlane(tid >> 7);   // 0..3
    const int e0     = q2u * 32;
    const int kb     = q2u * 26;

    const float* emb = node_emb + (size_t)b * NN * E_;

    // ---------------- prologue ----------------
    if (tid < E_) {
        const float* ge = graph_emb + (size_t)b * E_;
        double acc = 0.0;
        for (int g = 0; g < E_; ++g)
            acc += (double)ge[g] * (double)Wq_fixed[g * E_ + tid];
        sQfix64[tid] = acc;
        sQfix32[tid] = (float)acc;
        sWqD64[tid]  = (double)Wq_step[128 * E_ + tid];
        sWqD32[tid]  = Wq_step[128 * E_ + tid];
    }
    if (tid < 2 * NN) {
        int k = tid >> 1, xy = tid & 1;
        sCoord[tid] = (k == 0) ? depot_xy[(size_t)b * 2 + xy]
                               : customer_xy[((size_t)b * NC + (k - 1)) * 2 + xy];
    }
    if (tid < NC) sDem[tid] = demand[(size_t)b * NC + tid];
    if (tid == 0) {
        sD = 1.f; sPrev = 0; sVis0 = 0ull; sVis1 = 0ull;
        sMaskDepot = 1; sCost = 0.0; sLL = 0.0; sTrig = 0; sOvf = 0;
        sPosX = depot_xy[(size_t)b * 2 + 0];
        sPosY = depot_xy[(size_t)b * 2 + 1];
    }

    // V into LDS; Kstep into gks (global, L2-resident) if available
    for (int idx = tid; idx < NN * 32; idx += 512) {
        int k  = idx >> 5;
        int e4 = (idx & 31) * 4;
        const float* er = emb + (size_t)k * E_;
        float4 aV = {0.f, 0.f, 0.f, 0.f};
        float4 aK = {0.f, 0.f, 0.f, 0.f};
        for (int g = 0; g < E_; ++g) {
            float eg = er[g];
            float4 wv = *(const float4*)(Wv + (size_t)g * E_ + e4);
            aV.x += eg * wv.x; aV.y += eg * wv.y;
            aV.z += eg * wv.z; aV.w += eg * wv.w;
            if (gks) {
                float4 wq = *(const float4*)(Wq_step + (size_t)g * E_ + e4);
                aK.x += eg * wq.x; aK.y += eg * wq.y;
                aK.z += eg * wq.z; aK.w += eg * wq.w;
            }
        }
        *(float4*)(sV + (size_t)k * E_ + e4) = aV;
        if (gks)
            *(float4*)(gks + ((size_t)b * NN + k) * E_ + e4) = aK;
    }

    // Per-wave K1h fragment (head h, nodes k=lane and k=lane+64)
    float rA[32];
#pragma unroll
    for (int j = 0; j < 32; ++j) rA[j] = 0.f;
    {
        const float* er0 = emb + (size_t)lane * E_;
        const float* er1 = emb + (size_t)((k1 < NN) ? k1 : lane) * E_;
        const float  e1s = (k1 < NN) ? 1.f : 0.f;
        const float* w1b = Wk1 + h * 16;
        for (int g = 0; g < E_; ++g) {
            float a0 = er0[g];
            float a1 = er1[g] * e1s;
            const float* w1 = w1b + (size_t)g * E_;
#pragma unroll
            for (int d = 0; d < 16; ++d) {
                rA[d]      += a0 * w1[d];
                rA[16 + d] += a1 * w1[d];
            }
        }
    }

    // K2t chunk (32 cols) into registers
    float rK2[32];
#pragma unroll
    for (int j = 0; j < 32; ++j) rK2[j] = 0.f;
    if (k_lane < NN) {
        const float* er = emb + (size_t)k_lane * E_;
        for (int g = 0; g < E_; ++g) {
            float eg = er[g];
            const float* mm = M32 + (size_t)g * E_ + e0;
#pragma unroll
            for (int j = 0; j < 32; ++j) rK2[j] += eg * mm[j];
        }
    }
    __syncthreads();

    // ---------------- sequential decode loop ----------------
    for (int t = 0; t < T_; ++t) {
        // ---- A (only when no gks): q1 into LDS ----
        if (!gks) {
            if (tid < E_) {
                const float* ep = emb + (size_t)sPrev * E_;
                float ks = 0.f;
                for (int g = 0; g < E_; ++g)
                    ks += ep[g] * Wq_step[(size_t)g * E_ + tid];
                fQ1[tid] = (sQfix32[tid] + ks + sD * sWqD32[tid]) * 0.25f;
            }
            __syncthreads();
        }

        // ---- B (per-wave): q1 slice + scores + exp + head sum ----
        {
            int prev = sPrev;
            float Dv = sD;
            int d_ = h * 16 + (lane & 15);
            float q1v;
            if (gks) {
                float ksv = gks[((size_t)b * NN + prev) * E_ + d_];
                q1v = (sQfix32[d_] + ksv + Dv * sWqD32[d_]) * 0.25f;
            } else {
                q1v = fQ1[d_];
            }

            unsigned long long v0 = sVis0, v1 = sVis1;
            bool mk0, mk1;
            if (lane == 0) mk0 = (sMaskDepot != 0);
            else {
                int c = lane - 1;   // 0..62 -> always in sVis0
                mk0 = ((v0 >> c) & 1ull) || (sDem[c] > Dv);
            }
            if (k1 < NN) {
                int c = k1 - 1;     // 63..99
                bool vis = (c < 64) ? ((v0 >> c) & 1ull)
                                    : ((v1 >> (c - 64)) & 1ull);
                mk1 = vis || (sDem[c] > Dv);
            } else mk1 = true;

            float s0 = 0.f, s1 = 0.f;
#pragma unroll
            for (int d = 0; d < 16; ++d) {
                float qd = rdlane(q1v, d);
                s0 += rA[d] * qd;
                s1 += rA[16 + d] * qd;
            }
            bool ovf = (!mk0 && s0 > 80.f) || (!mk1 && s1 > 80.f);
            if (__any(ovf)) { if (lane == 0) sOvf = 1; }
            float w0 = mk0 ? 0.f : expf(fminf(s0, 80.f));
            float w1 = mk1 ? 0.f : expf(fminf(s1, 80.f));
            fSc[h * 104 + lane] = w0;
            if (k1 < 104) fSc[h * 104 + k1] = w1;
            float wsum = w0 + w1;
#pragma unroll
            for (int m = 32; m >= 1; m >>= 1) wsum += __shfl_xor(wsum, m);
            if (lane == 0) sInvS[h] = 1.0f / wsum;
        }
        __syncthreads();

        // ---- C: glimpse partials over 4 k-chunks (LDS sV) ----
        {
            int e = k_lane, hh = e >> 4;
            const float* sc = fSc + hh * 104 + kb;
            const float* vv = sV + (size_t)kb * E_ + e;
            float p = 0.f;
#pragma unroll
            for (int j = 0; j < 26; ++j) p += sc[j] * vv[j * E_];
            fPart[q2u * E_ + e] = p;
        }
        __syncthreads();

        // ---- D: logits via readlane dot (normalized glimpse in-flight) ----
        {
            int ee = e0 + (tid & 31);
            float glv = (fPart[ee] + fPart[128 + ee] + fPart[256 + ee]
                         + fPart[384 + ee]) * sInvS[ee >> 4];
            float x = 0.f;
#pragma unroll
            for (int j = 0; j < 32; ++j) x += rK2[j] * rdlane(glv, j);
            if (k_lane < NN) fPx[q2u * E_ + k_lane] = x;
        }
        __syncthreads();

        // ---- E: top-2 argmax (pre-tanh), gap test, commit-or-trigger ----
        if (tid < 64) {
            int kA = tid, kB = tid + 64;
            float xA = (fPx[kA] + fPx[128 + kA] + fPx[256 + kA] + fPx[384 + kA]) * INVSQE;
            bool mk1;
            if (kA == 0) mk1 = (sMaskDepot != 0);
            else {
                int c = kA - 1;
                bool vis = (c < 64) ? ((sVis0 >> c) & 1ull) : ((sVis1 >> (c - 64)) & 1ull);
                mk1 = vis || (sDem[c] > sD);
            }
            float xB = -3.0e38f; bool mk2 = true;
            if (kB < NN) {
                xB = (fPx[kB] + fPx[128 + kB] + fPx[256 + kB] + fPx[384 + kB]) * INVSQE;
                int c = kB - 1;
                bool vis = (c < 64) ? ((sVis0 >> c) & 1ull) : ((sVis1 >> (c - 64)) & 1ull);
                mk2 = vis || (sDem[c] > sD);
            }
            float a1v = mk1 ? -3.0e38f : xA;
            float a2v = mk2 ? -3.0e38f : xB;
            float m1, m2; int mi;
            if (a2v > a1v) { m1 = a2v; m2 = a1v; mi = kB; }
            else           { m1 = a1v; m2 = a2v; mi = kA; }
            float ls = 0.f;
            if (!mk1)              ls += expf(10.f * tanhf(xA));
            if (kB < NN && !mk2)   ls += expf(10.f * tanhf(xB));
#pragma unroll
            for (int off = 32; off > 0; off >>= 1) {
                float om1 = __shfl_xor(m1, off);
                float om2 = __shfl_xor(m2, off);
                float os  = __shfl_xor(ls, off);
                int   omi = __shfl_xor(mi, off);
                ls += os;
                if (om1 > m1 || (om1 == m1 && omi < mi)) {
                    m2 = fmaxf(m1, om2); m1 = om1; mi = omi;
                } else {
                    m2 = fmaxf(m2, om1);
                }
            }
            if (tid == 0) {
                float gap = m1 - m2;
                bool trig = !(gap >= GAPTHR) || (sOvf != 0);   // NaN-safe
                sOvf = 0;
                if (trig) {
                    sTrig = 1;
                } else {
                    float lsel = 10.f * tanhf(m1);
                    float logp = lsel - logf(ls);
                    int nxt = mi;
                    sLL += (double)logp;
                    bool isdep = (nxt == 0);
                    if (isdep) {
                        sD = 1.0f;
                    } else {
                        int c = nxt - 1;
                        sD = sD - sDem[c];
                        if (c < 64) sVis0 |= (1ull << c);
                        else        sVis1 |= (1ull << (c - 64));
                    }
                    bool allv = (sVis0 == 0xFFFFFFFFFFFFFFFFull) &&
                                (sVis1 == 0x0000000FFFFFFFFFull);
                    sMaskDepot = (isdep && !allv) ? 1 : 0;
                    sPrev = nxt;
                    float cx = sCoord[2 * nxt], cy = sCoord[2 * nxt + 1];
                    double dx = (double)cx - (double)sPosX;
                    double dy = (double)cy - (double)sPosY;
                    sCost += sqrt(dx * dx + dy * dy + 1e-10);
                    sPosX = cx; sPosY = cy;
                }
            }
        }
        __syncthreads();

        // ---- Fallback: exact fp64 recompute of this step (rare) ----
        if (sTrig) {
            // F0: q1d
            if (tid < E_) {
                const float* ep = emb + (size_t)sPrev * E_;
                double ks = 0.0;
                for (int g = 0; g < E_; ++g)
                    ks += (double)ep[g] * (double)Wq_step[(size_t)g * E_ + tid];
                dQ1[tid] = (sQfix64[tid] + ks + (double)sD * sWqD64[tid]) * 0.25;
            }
            __syncthreads();
            // F1: u1[g][h]
            for (int idx = tid; idx < 1024; idx += 512) {
                int g = idx >> 3, hh = idx & 7;
                double u = 0.0;
#pragma unroll 4
                for (int d = 0; d < 16; ++d)
                    u += dQ1[hh * 16 + d] * (double)Wk1[(size_t)g * E_ + hh * 16 + d];
                dUZ[idx] = u;
            }
            __syncthreads();
            // F2: scores
            for (int idx = tid; idx < 1024; idx += 512) {
                int k = idx & 127, hh = idx >> 7;
                if (k < NN) {
                    bool mk;
                    if (k == 0) mk = (sMaskDepot != 0);
                    else {
                        int c = k - 1;
                        bool vis = (c < 64) ? ((sVis0 >> c) & 1ull) : ((sVis1 >> (c - 64)) & 1ull);
                        mk = vis || (sDem[c] > sD);
                    }
                    if (mk) dSc[hh * NN + k] = NEGV;
                    else {
                        const float* ek = emb + (size_t)k * E_;
                        double s = 0.0;
                        for (int g = 0; g < E_; ++g)
                            s += (double)ek[g] * dUZ[g * 8 + hh];
                        dSc[hh * NN + k] = s;
                    }
                }
            }
            __syncthreads();
            // F3: per-head softmax (wave hh), normalized weights in place
            {
                int hh = tid >> 6, ln = tid & 63;
                int kA = ln, kB = ln + 64;
                double v1 = dSc[hh * NN + kA];
                double v2 = (kB < NN) ? dSc[hh * NN + kB] : -1.0e300;
                double m = fmax(v1, v2);
#pragma unroll
                for (int off = 32; off > 0; off >>= 1)
                    m = fmax(m, __shfl_xor(m, off));
                double e1 = exp(v1 - m);
                double e2 = (kB < NN) ? exp(v2 - m) : 0.0;
                double s = e1 + e2;
#pragma unroll
                for (int off = 32; off > 0; off >>= 1)
                    s += __shfl_xor(s, off);
                double inv = 1.0 / s;
                dSc[hh * NN + kA] = e1 * inv;
                if (kB < NN) dSc[hh * NN + kB] = e2 * inv;
            }
            __syncthreads();
            // F4: z[g][h] = sum_k w[h][k] emb[k][g]
            for (int idx = tid; idx < 1024; idx += 512) {
                int g = idx >> 3, hh = idx & 7;
                double z = 0.0;
                for (int k = 0; k < NN; ++k)
                    z += dSc[hh * NN + k] * (double)emb[(size_t)k * E_ + g];
                dUZ[idx] = z;
            }
            __syncthreads();
            // F5: glimpse
            if (tid < E_) {
                int hh = tid >> 4;
                double g2 = 0.0;
                for (int g = 0; g < E_; ++g)
                    g2 += dUZ[g * 8 + hh] * (double)Wv[(size_t)g * E_ + tid];
                dGl[tid] = g2;
            }
            __syncthreads();
            // F6: vg = M64 @ glimpse
            if (tid < E_) {
                double v = 0.0;
                for (int e = 0; e < E_; ++e)
                    v += dGl[e] * M64[(size_t)tid * E_ + e];
                dVg[tid] = v;
            }
            __syncthreads();
            // F7: xd[k] (reuse dQ1)
            if (tid < NN) {
                const float* ek = emb + (size_t)tid * E_;
                double x = 0.0;
                for (int g = 0; g < E_; ++g)
                    x += (double)ek[g] * dVg[g];
                dQ1[tid] = x * INVSQED;
            }
            __syncthreads();
            // F8: fp64 argmax + LSE + commit
            if (tid < 64) {
                int kA = tid, kB = tid + 64;
                double x1 = dQ1[kA];
                bool mk1;
                if (kA == 0) mk1 = (sMaskDepot != 0);
                else {
                    int c = kA - 1;
                    bool vis = (c < 64) ? ((sVis0 >> c) & 1ull) : ((sVis1 >> (c - 64)) & 1ull);
                    mk1 = vis || (sDem[c] > sD);
                }
                double x2 = 0.0; bool mk2 = true;
                if (kB < NN) {
                    x2 = dQ1[kB];
                    int c = kB - 1;
                    bool vis = (c < 64) ? ((sVis0 >> c) & 1ull) : ((sVis1 >> (c - 64)) & 1ull);
                    mk2 = vis || (sDem[c] > sD);
                }
                double a1 = mk1 ? -1.0e300 : x1;
                double a2 = (kB < NN && !mk2) ? x2 : -1.0e300;
                double mv; int mi;
                if (a1 >= a2) { mv = a1; mi = kA; } else { mv = a2; mi = kB; }
#pragma unroll
                for (int off = 32; off > 0; off >>= 1) {
                    double ov = __shfl_xor(mv, off);
                    int    oi = __shfl_xor(mi, off);
                    if (ov > mv || (ov == mv && oi < mi)) { mv = ov; mi = oi; }
                }
                double lmax = 10.0 * tanh(mv);
                double l1 = mk1 ? NEGV : 10.0 * tanh(x1);
                double l2 = (kB < NN) ? (mk2 ? NEGV : 10.0 * tanh(x2)) : 0.0;
                double s = exp(l1 - lmax) + ((kB < NN) ? exp(l2 - lmax) : 0.0);
#pragma unroll
                for (int off = 32; off > 0; off >>= 1)
                    s += __shfl_xor(s, off);
                if (tid == 0) {
                    int nxt = mi;
                    sLL += -log(s);
                    bool isdep = (nxt == 0);
                    if (isdep) {
                        sD = 1.0f;
                    } else {
                        int c = nxt - 1;
                        sD = sD - sDem[c];
                        if (c < 64) sVis0 |= (1ull << c);
                        else        sVis1 |= (1ull << (c - 64));
                    }
                    bool allv = (sVis0 == 0xFFFFFFFFFFFFFFFFull) &&
                                (sVis1 == 0x0000000FFFFFFFFFull);
                    sMaskDepot = (isdep && !allv) ? 1 : 0;
                    sPrev = nxt;
                    float cx = sCoord[2 * nxt], cy = sCoord[2 * nxt + 1];
                    double dx = (double)cx - (double)sPosX;
                    double dy = (double)cy - (double)sPosY;
                    sCost += sqrt(dx * dx + dy * dy + 1e-10);
                    sPosX = cx; sPosY = cy;
                    sTrig = 0;
                }
            }
            __syncthreads();
        }
    }

    if (tid == 0) {
        double dx = (double)sCoord[0] - (double)sPosX;
        double dy = (double)sCoord[1] - (double)sPosY;
        out[b]      = (float)(sCost + sqrt(dx * dx + dy * dy + 1e-10));
        out[B_ + b] = (float)sLL;
    }
}

// ---------------------------------------------------------------------------
extern "C" void kernel_launch(void* const* d_in, const int* in_sizes, int n_in,
                              void* d_out, int out_size, void* d_ws, size_t ws_size,
                              hipStream_t stream) {
    const float* depot = (const float*)d_in[0];
    const float* cust  = (const float*)d_in[1];
    const float* dem   = (const float*)d_in[2];
    const float* nemb  = (const float*)d_in[3];
    const float* gemb  = (const float*)d_in[4];
    const float* Wk1   = (const float*)d_in[5];
    const float* Wv    = (const float*)d_in[6];
    const float* Wk2   = (const float*)d_in[7];
    const float* Wqf   = (const float*)d_in[8];
    const float* Wout  = (const float*)d_in[9];
    const float* Wqs   = (const float*)d_in[10];
    float*  out = (float*)d_out;
    double* M64 = (double*)d_ws;                       // 128 KB
    float*  M32 = (float*)((char*)d_ws + 131072);      // 64 KB

    // Kstep workspace: [B][101][128] fp32 = 52.95 MB, if ws is big enough
    const size_t gks_off   = 196608;
    const size_t gks_bytes = (size_t)B_ * NN * E_ * sizeof(float);
    float* gks = (ws_size >= gks_off + gks_bytes)
               ? (float*)((char*)d_ws + gks_off) : nullptr;

    k_weights<<<dim3(128), dim3(128), 0, stream>>>(Wk2, Wout, M64, M32);
    k_decode <<<dim3(B_),  dim3(512), 0, stream>>>(depot, cust, dem, nemb, gemb,
                                                   Wk1, Wv, Wqf, Wqs, M64, M32,
                                                   gks, out);
}

// Round 9
// 4077.874 us; speedup vs baseline: 1.2061x; 1.2061x over previous
//
#include <hip/hip_runtime.h>
#include <math.h>

// Problem constants (match reference)
#define B_   1024
#define NC   100
#define NN   101          // N = NC + 1
#define E_   128
#define T_   202          // 2*N
#define NEGV   -1.0e9
#define GAPTHR 4.0e-3f    // fp32-path error bound ~3e-4 -> 13x margin
#define INVSQE 0.08838834764831845f
#define INVSQED 0.08838834764831845

__device__ __forceinline__ float rdlane(float v, int l) {
    return __int_as_float(__builtin_amdgcn_readlane(__float_as_int(v), l));
}

// ---------------------------------------------------------------------------
// kernel 0: M = Wk2 @ Wout^T (128x128) into ws as fp64 (fallback) + fp32 (fast)
// ---------------------------------------------------------------------------
__global__ void k_weights(const float* __restrict__ Wk2,
                          const float* __restrict__ Wout,
                          double* __restrict__ M64,
                          float* __restrict__ M32) {
    int g = blockIdx.x;   // 0..127
    int e = threadIdx.x;  // 0..127
    const float* w2 = Wk2 + g * E_;
    const float* wo = Wout + e * E_;
    double acc = 0.0;
#pragma unroll 8
    for (int f = 0; f < E_; ++f) acc += (double)w2[f] * (double)wo[f];
    M64[g * E_ + e] = acc;
    M32[g * E_ + e] = (float)acc;
}

// ---------------------------------------------------------------------------
// kernel 1: per-batch score tables.
//   KK[b][h][p][k] = 0.25 * (Kstep[p] . K1h[k]) + A0[h][k]   (A0 folded in)
//   B0[b][h][k]    = 0.25 * (WqD . K1h[k])
// where Kstep = emb @ Wq_step[:128], K1 = emb @ Wk1, A0 = 0.25*(Qfix . K1h).
// One block per batch element.
// ---------------------------------------------------------------------------
__global__ __launch_bounds__(512, 1)
void k_prep(const float* __restrict__ node_emb,
            const float* __restrict__ graph_emb,
            const float* __restrict__ Wk1,
            const float* __restrict__ Wq_step,
            const float* __restrict__ Wq_fixed,
            float* __restrict__ KK,
            float* __restrict__ B0g)
{
    __shared__ float sKs[NN * E_];   // 51.7 KB
    __shared__ float sK1[NN * E_];   // 51.7 KB
    __shared__ float sQf[E_];

    const int b   = blockIdx.x;
    const int tid = threadIdx.x;
    const float* emb = node_emb + (size_t)b * NN * E_;

    // Qfix (fp64 accumulate, store fp32)
    if (tid < E_) {
        const float* ge = graph_emb + (size_t)b * E_;
        double acc = 0.0;
        for (int g = 0; g < E_; ++g)
            acc += (double)ge[g] * (double)Wq_fixed[g * E_ + tid];
        sQf[tid] = (float)acc;
    }

    // Kstep and K1 into LDS (float4 over columns)
    for (int idx = tid; idx < NN * 32; idx += 512) {
        int k  = idx >> 5;
        int e4 = (idx & 31) * 4;
        const float* er = emb + (size_t)k * E_;
        float4 aK = {0.f, 0.f, 0.f, 0.f};
        float4 a1 = {0.f, 0.f, 0.f, 0.f};
        for (int g = 0; g < E_; ++g) {
            float eg = er[g];
            float4 wq = *(const float4*)(Wq_step + (size_t)g * E_ + e4);
            float4 w1 = *(const float4*)(Wk1     + (size_t)g * E_ + e4);
            aK.x += eg * wq.x; aK.y += eg * wq.y;
            aK.z += eg * wq.z; aK.w += eg * wq.w;
            a1.x += eg * w1.x; a1.y += eg * w1.y;
            a1.z += eg * w1.z; a1.w += eg * w1.w;
        }
        *(float4*)(sKs + (size_t)k * E_ + e4) = aK;
        *(float4*)(sK1 + (size_t)k * E_ + e4) = a1;
    }
    __syncthreads();

    // wave h = tid>>6 handles head h; lane owns nodes k0=lane, k1=lane+64
    const int lane = tid & 63;
    const int h    = __builtin_amdgcn_readfirstlane(tid >> 6);
    const int k0   = lane;
    const int k1i  = lane + 64;
    const bool has1 = (k1i < NN);

    float f0[16], f1[16];
#pragma unroll
    for (int j = 0; j < 16; ++j) f0[j] = sK1[(size_t)k0 * E_ + h * 16 + j];
#pragma unroll
    for (int j = 0; j < 16; ++j) f1[j] = has1 ? sK1[(size_t)k1i * E_ + h * 16 + j] : 0.f;

    // A0, B0
    float a00 = 0.f, a01 = 0.f, b00 = 0.f, b01 = 0.f;
#pragma unroll
    for (int j = 0; j < 16; ++j) {
        float qf = sQf[h * 16 + j];
        float wd = Wq_step[128 * E_ + h * 16 + j];
        a00 += qf * f0[j]; a01 += qf * f1[j];
        b00 += wd * f0[j]; b01 += wd * f1[j];
    }
    a00 *= 0.25f; a01 *= 0.25f; b00 *= 0.25f; b01 *= 0.25f;

    float* b0r = B0g + ((size_t)b * 8 + h) * NN;
    b0r[k0] = b00;
    if (has1) b0r[k1i] = b01;

    // KK rows (coalesced writes: lanes write adjacent k)
    float* kkb = KK + (((size_t)b * 8 + h) * NN) * NN;
    for (int p = 0; p < NN; ++p) {
        float s0 = 0.f, s1 = 0.f;
        const float* ksr = sKs + (size_t)p * E_ + h * 16;
#pragma unroll
        for (int j = 0; j < 16; ++j) {
            float ks = ksr[j];           // uniform (broadcast) LDS read
            s0 += ks * f0[j];
            s1 += ks * f1[j];
        }
        float* kkr = kkb + (size_t)p * NN;
        kkr[k0] = s0 * 0.25f + a00;
        if (has1) kkr[k1i] = s1 * 0.25f + a01;
    }
}

// ---------------------------------------------------------------------------
// Fast decoder (KK tables). 1 block / batch element, 512 threads (8 waves).
// LDS ~73 KB, register arrays = rK2[32] only -> targets 2 blocks/CU.
// Phase B: scores = KK[h][prev][k] + D*B0[h][k] (2 coalesced loads + FMA).
// 4 barriers/step. Exact fp64 fallback on near-tie argmax (gap < GAPTHR).
// ---------------------------------------------------------------------------
__global__ __launch_bounds__(512, 4)
void k_decode_kk(const float* __restrict__ depot_xy,
                 const float* __restrict__ customer_xy,
                 const float* __restrict__ demand,
                 const float* __restrict__ node_emb,
                 const float* __restrict__ graph_emb,
                 const float* __restrict__ Wk1,
                 const float* __restrict__ Wv,
                 const float* __restrict__ Wq_fixed,
                 const float* __restrict__ Wq_step,
                 const double* __restrict__ M64,
                 const float* __restrict__ M32,
                 const float* __restrict__ KK,
                 const float* __restrict__ B0g,
                 float* __restrict__ out)          // [2*B]: cost then ll
{
    __shared__ float  sV [NN * E_];             // 51.7 KB V rows fp32
    __shared__ double sU[2224];                 // union scratch 17.8 KB
    __shared__ double sQfix64[E_];
    __shared__ double sWqD64[E_];
    __shared__ float  sInvS[8];
    __shared__ float  sCoord[2 * NN];
    __shared__ float  sDem[NC];
    __shared__ float  sD;
    __shared__ double sCost, sLL;
    __shared__ float  sPosX, sPosY;
    __shared__ int    sPrev, sMaskDepot, sTrig, sOvf;
    __shared__ unsigned long long sVis0, sVis1;

    // fast fp32 views (overlay the fp64 fallback scratch)
    float* fSc   = (float*)sU;          // [8][104] exp-scores (pads 101..103)
    float* fPart = (float*)sU + 832;    // [4][128] glimpse partials
    float* fPx   = (float*)sU + 1344;   // [4][128] logit partials
    // fallback fp64 views
    double* dUZ = sU;                   // [128][8] u1 then z
    double* dSc = sU + 1024;            // [8][101] scores -> weights
    double* dQ1 = sU + 1832;            // [128] q1, later xd[101]
    double* dGl = sU + 1960;            // [128]
    double* dVg = sU + 2088;            // [128]

    const int b      = blockIdx.x;
    const int tid    = threadIdx.x;
    const int lane   = tid & 63;
    const int h      = __builtin_amdgcn_readfirstlane(tid >> 6);   // head 0..7
    const int k1     = lane + 64;                                  // 2nd node
    const int k_lane = tid & 127;
    const int q2u    = __builtin_amdgcn_readfirstlane(tid >> 7);   // 0..3
    const int e0     = q2u * 32;
    const int kb     = q2u * 26;

    const float* emb = node_emb + (size_t)b * NN * E_;
    const float* kkb = KK + (((size_t)b * 8 + h) * NN) * NN;

    // ---------------- prologue ----------------
    if (tid < E_) {
        const float* ge = graph_emb + (size_t)b * E_;
        double acc = 0.0;
        for (int g = 0; g < E_; ++g)
            acc += (double)ge[g] * (double)Wq_fixed[g * E_ + tid];
        sQfix64[tid] = acc;
        sWqD64[tid]  = (double)Wq_step[128 * E_ + tid];
    }
    if (tid < 2 * NN) {
        int k = tid >> 1, xy = tid & 1;
        sCoord[tid] = (k == 0) ? depot_xy[(size_t)b * 2 + xy]
                               : customer_xy[((size_t)b * NC + (k - 1)) * 2 + xy];
    }
    if (tid < NC) sDem[tid] = demand[(size_t)b * NC + tid];
    if (tid == 0) {
        sD = 1.f; sPrev = 0; sVis0 = 0ull; sVis1 = 0ull;
        sMaskDepot = 1; sCost = 0.0; sLL = 0.0; sTrig = 0; sOvf = 0;
        sPosX = depot_xy[(size_t)b * 2 + 0];
        sPosY = depot_xy[(size_t)b * 2 + 1];
    }

    // B0 rows hoisted into registers (loop-invariant)
    float rB0a, rB0b;
    {
        const float* b0r = B0g + ((size_t)b * 8 + h) * NN;
        rB0a = b0r[lane];
        rB0b = (k1 < NN) ? b0r[k1] : 0.f;
    }

    // V into LDS (fp32, float4 over columns)
    for (int idx = tid; idx < NN * 32; idx += 512) {
        int k  = idx >> 5;
        int e4 = (idx & 31) * 4;
        const float* er = emb + (size_t)k * E_;
        float4 aV = {0.f, 0.f, 0.f, 0.f};
        for (int g = 0; g < E_; ++g) {
            float eg = er[g];
            float4 wv = *(const float4*)(Wv + (size_t)g * E_ + e4);
            aV.x += eg * wv.x; aV.y += eg * wv.y;
            aV.z += eg * wv.z; aV.w += eg * wv.w;
        }
        *(float4*)(sV + (size_t)k * E_ + e4) = aV;
    }

    // K2t chunk (32 cols) into registers
    float rK2[32];
#pragma unroll
    for (int j = 0; j < 32; ++j) rK2[j] = 0.f;
    if (k_lane < NN) {
        const float* er = emb + (size_t)k_lane * E_;
        for (int g = 0; g < E_; ++g) {
            float eg = er[g];
            const float* mm = M32 + (size_t)g * E_ + e0;
#pragma unroll
            for (int j = 0; j < 32; ++j) rK2[j] += eg * mm[j];
        }
    }
    __syncthreads();

    // ---------------- sequential decode loop ----------------
    for (int t = 0; t < T_; ++t) {
        // ---- B (per-wave): table-lookup scores + exp + head sum ----
        {
            int prev = sPrev;
            float Dv = sD;
            const float* kkr = kkb + (size_t)prev * NN;
            float kk0 = kkr[lane];
            float kk1v = (k1 < NN) ? kkr[k1] : 0.f;

            unsigned long long v0 = sVis0, v1 = sVis1;
            bool mk0, mk1;
            if (lane == 0) mk0 = (sMaskDepot != 0);
            else {
                int c = lane - 1;   // 0..62 -> always in sVis0
                mk0 = ((v0 >> c) & 1ull) || (sDem[c] > Dv);
            }
            if (k1 < NN) {
                int c = k1 - 1;     // 63..99
                bool vis = (c < 64) ? ((v0 >> c) & 1ull)
                                    : ((v1 >> (c - 64)) & 1ull);
                mk1 = vis || (sDem[c] > Dv);
            } else mk1 = true;

            float s0 = kk0 + Dv * rB0a;
            float s1 = kk1v + Dv * rB0b;

            bool ovf = (!mk0 && s0 > 80.f) || (!mk1 && s1 > 80.f);
            if (__any(ovf)) { if (lane == 0) sOvf = 1; }
            float w0 = mk0 ? 0.f : expf(fminf(s0, 80.f));
            float w1 = mk1 ? 0.f : expf(fminf(s1, 80.f));
            fSc[h * 104 + lane] = w0;
            if (k1 < 104) fSc[h * 104 + k1] = w1;
            float wsum = w0 + w1;
#pragma unroll
            for (int m = 32; m >= 1; m >>= 1) wsum += __shfl_xor(wsum, m);
            if (lane == 0) sInvS[h] = 1.0f / wsum;
        }
        __syncthreads();

        // ---- C: glimpse partials over 4 k-chunks (LDS sV) ----
        {
            int e = k_lane, hh = e >> 4;
            const float* sc = fSc + hh * 104 + kb;
            const float* vv = sV + (size_t)kb * E_ + e;
            float p = 0.f;
#pragma unroll
            for (int j = 0; j < 26; ++j) p += sc[j] * vv[j * E_];
            fPart[q2u * E_ + e] = p;
        }
        __syncthreads();

        // ---- D: logits via readlane dot (normalized glimpse in-flight) ----
        {
            int ee = e0 + (tid & 31);
            float glv = (fPart[ee] + fPart[128 + ee] + fPart[256 + ee]
                         + fPart[384 + ee]) * sInvS[ee >> 4];
            float x = 0.f;
#pragma unroll
            for (int j = 0; j < 32; ++j) x += rK2[j] * rdlane(glv, j);
            if (k_lane < NN) fPx[q2u * E_ + k_lane] = x;
        }
        __syncthreads();

        // ---- E: top-2 argmax (pre-tanh), gap test, commit-or-trigger ----
        if (tid < 64) {
            int kA = tid, kB = tid + 64;
            float xA = (fPx[kA] + fPx[128 + kA] + fPx[256 + kA] + fPx[384 + kA]) * INVSQE;
            bool mk1;
            if (kA == 0) mk1 = (sMaskDepot != 0);
            else {
                int c = kA - 1;
                bool vis = (c < 64) ? ((sVis0 >> c) & 1ull) : ((sVis1 >> (c - 64)) & 1ull);
                mk1 = vis || (sDem[c] > sD);
            }
            float xB = -3.0e38f; bool mk2 = true;
            if (kB < NN) {
                xB = (fPx[kB] + fPx[128 + kB] + fPx[256 + kB] + fPx[384 + kB]) * INVSQE;
                int c = kB - 1;
                bool vis = (c < 64) ? ((sVis0 >> c) & 1ull) : ((sVis1 >> (c - 64)) & 1ull);
                mk2 = vis || (sDem[c] > sD);
            }
            float a1v = mk1 ? -3.0e38f : xA;
            float a2v = mk2 ? -3.0e38f : xB;
            float m1, m2; int mi;
            if (a2v > a1v) { m1 = a2v; m2 = a1v; mi = kB; }
            else           { m1 = a1v; m2 = a2v; mi = kA; }
            float ls = 0.f;
            if (!mk1)              ls += expf(10.f * tanhf(xA));
            if (kB < NN && !mk2)   ls += expf(10.f * tanhf(xB));
#pragma unroll
            for (int off = 32; off > 0; off >>= 1) {
                float om1 = __shfl_xor(m1, off);
                float om2 = __shfl_xor(m2, off);
                float os  = __shfl_xor(ls, off);
                int   omi = __shfl_xor(mi, off);
                ls += os;
                if (om1 > m1 || (om1 == m1 && omi < mi)) {
                    m2 = fmaxf(m1, om2); m1 = om1; mi = omi;
                } else {
                    m2 = fmaxf(m2, om1);
                }
            }
            if (tid == 0) {
                float gap = m1 - m2;
                bool trig = !(gap >= GAPTHR) || (sOvf != 0);   // NaN-safe
                sOvf = 0;
                if (trig) {
                    sTrig = 1;
                } else {
                    float lsel = 10.f * tanhf(m1);
                    float logp = lsel - logf(ls);
                    int nxt = mi;
                    sLL += (double)logp;
                    bool isdep = (nxt == 0);
                    if (isdep) {
                        sD = 1.0f;
                    } else {
                        int c = nxt - 1;
                        sD = sD - sDem[c];
                        if (c < 64) sVis0 |= (1ull << c);
                        else        sVis1 |= (1ull << (c - 64));
                    }
                    bool allv = (sVis0 == 0xFFFFFFFFFFFFFFFFull) &&
                                (sVis1 == 0x0000000FFFFFFFFFull);
                    sMaskDepot = (isdep && !allv) ? 1 : 0;
                    sPrev = nxt;
                    float cx = sCoord[2 * nxt], cy = sCoord[2 * nxt + 1];
                    double dx = (double)cx - (double)sPosX;
                    double dy = (double)cy - (double)sPosY;
                    sCost += sqrt(dx * dx + dy * dy + 1e-10);
                    sPosX = cx; sPosY = cy;
                }
            }
        }
        __syncthreads();

        // ---- Fallback: exact fp64 recompute of this step (rare) ----
        if (sTrig) {
            if (tid < E_) {
                const float* ep = emb + (size_t)sPrev * E_;
                double ks = 0.0;
                for (int g = 0; g < E_; ++g)
                    ks += (double)ep[g] * (double)Wq_step[(size_t)g * E_ + tid];
                dQ1[tid] = (sQfix64[tid] + ks + (double)sD * sWqD64[tid]) * 0.25;
            }
            __syncthreads();
            for (int idx = tid; idx < 1024; idx += 512) {
                int g = idx >> 3, hh = idx & 7;
                double u = 0.0;
#pragma unroll 4
                for (int d = 0; d < 16; ++d)
                    u += dQ1[hh * 16 + d] * (double)Wk1[(size_t)g * E_ + hh * 16 + d];
                dUZ[idx] = u;
            }
            __syncthreads();
            for (int idx = tid; idx < 1024; idx += 512) {
                int k = idx & 127, hh = idx >> 7;
                if (k < NN) {
                    bool mk;
                    if (k == 0) mk = (sMaskDepot != 0);
                    else {
                        int c = k - 1;
                        bool vis = (c < 64) ? ((sVis0 >> c) & 1ull) : ((sVis1 >> (c - 64)) & 1ull);
                        mk = vis || (sDem[c] > sD);
                    }
                    if (mk) dSc[hh * NN + k] = NEGV;
                    else {
                        const float* ek = emb + (size_t)k * E_;
                        double s = 0.0;
                        for (int g = 0; g < E_; ++g)
                            s += (double)ek[g] * dUZ[g * 8 + hh];
                        dSc[hh * NN + k] = s;
                    }
                }
            }
            __syncthreads();
            {
                int hh = tid >> 6, ln = tid & 63;
                int kA = ln, kB = ln + 64;
                double v1 = dSc[hh * NN + kA];
                double v2 = (kB < NN) ? dSc[hh * NN + kB] : -1.0e300;
                double m = fmax(v1, v2);
#pragma unroll
                for (int off = 32; off > 0; off >>= 1)
                    m = fmax(m, __shfl_xor(m, off));
                double e1 = exp(v1 - m);
                double e2 = (kB < NN) ? exp(v2 - m) : 0.0;
                double s = e1 + e2;
#pragma unroll
                for (int off = 32; off > 0; off >>= 1)
                    s += __shfl_xor(s, off);
                double inv = 1.0 / s;
                dSc[hh * NN + kA] = e1 * inv;
                if (kB < NN) dSc[hh * NN + kB] = e2 * inv;
            }
            __syncthreads();
            for (int idx = tid; idx < 1024; idx += 512) {
                int g = idx >> 3, hh = idx & 7;
                double z = 0.0;
                for (int k = 0; k < NN; ++k)
                    z += dSc[hh * NN + k] * (double)emb[(size_t)k * E_ + g];
                dUZ[idx] = z;
            }
            __syncthreads();
            if (tid < E_) {
                int hh = tid >> 4;
                double g2 = 0.0;
                for (int g = 0; g < E_; ++g)
                    g2 += dUZ[g * 8 + hh] * (double)Wv[(size_t)g * E_ + tid];
                dGl[tid] = g2;
            }
            __syncthreads();
            if (tid < E_) {
                double v = 0.0;
                for (int e = 0; e < E_; ++e)
                    v += dGl[e] * M64[(size_t)tid * E_ + e];
                dVg[tid] = v;
            }
            __syncthreads();
            if (tid < NN) {
                const float* ek = emb + (size_t)tid * E_;
                double x = 0.0;
                for (int g = 0; g < E_; ++g)
                    x += (double)ek[g] * dVg[g];
                dQ1[tid] = x * INVSQED;
            }
            __syncthreads();
            if (tid < 64) {
                int kA = tid, kB = tid + 64;
                double x1 = dQ1[kA];
                bool mk1;
                if (kA == 0) mk1 = (sMaskDepot != 0);
                else {
                    int c = kA - 1;
                    bool vis = (c < 64) ? ((sVis0 >> c) & 1ull) : ((sVis1 >> (c - 64)) & 1ull);
                    mk1 = vis || (sDem[c] > sD);
                }
                double x2 = 0.0; bool mk2 = true;
                if (kB < NN) {
                    x2 = dQ1[kB];
                    int c = kB - 1;
                    bool vis = (c < 64) ? ((sVis0 >> c) & 1ull) : ((sVis1 >> (c - 64)) & 1ull);
                    mk2 = vis || (sDem[c] > sD);
                }
                double a1 = mk1 ? -1.0e300 : x1;
                double a2 = (kB < NN && !mk2) ? x2 : -1.0e300;
                double mv; int mi;
                if (a1 >= a2) { mv = a1; mi = kA; } else { mv = a2; mi = kB; }
#pragma unroll
                for (int off = 32; off > 0; off >>= 1) {
                    double ov = __shfl_xor(mv, off);
                    int    oi = __shfl_xor(mi, off);
                    if (ov > mv || (ov == mv && oi < mi)) { mv = ov; mi = oi; }
                }
                double lmax = 10.0 * tanh(mv);
                double l1 = mk1 ? NEGV : 10.0 * tanh(x1);
                double l2 = (kB < NN) ? (mk2 ? NEGV : 10.0 * tanh(x2)) : 0.0;
                double s = exp(l1 - lmax) + ((kB < NN) ? exp(l2 - lmax) : 0.0);
#pragma unroll
                for (int off = 32; off > 0; off >>= 1)
                    s += __shfl_xor(s, off);
                if (tid == 0) {
                    int nxt = mi;
                    sLL += -log(s);
                    bool isdep = (nxt == 0);
                    if (isdep) {
                        sD = 1.0f;
                    } else {
                        int c = nxt - 1;
                        sD = sD - sDem[c];
                        if (c < 64) sVis0 |= (1ull << c);
                        else        sVis1 |= (1ull << (c - 64));
                    }
                    bool allv = (sVis0 == 0xFFFFFFFFFFFFFFFFull) &&
                                (sVis1 == 0x0000000FFFFFFFFFull);
                    sMaskDepot = (isdep && !allv) ? 1 : 0;
                    sPrev = nxt;
                    float cx = sCoord[2 * nxt], cy = sCoord[2 * nxt + 1];
                    double dx = (double)cx - (double)sPosX;
                    double dy = (double)cy - (double)sPosY;
                    sCost += sqrt(dx * dx + dy * dy + 1e-10);
                    sPosX = cx; sPosY = cy;
                    sTrig = 0;
                }
            }
            __syncthreads();
        }
    }

    if (tid == 0) {
        double dx = (double)sCoord[0] - (double)sPosX;
        double dy = (double)sCoord[1] - (double)sPosY;
        out[b]      = (float)(sCost + sqrt(dx * dx + dy * dy + 1e-10));
        out[B_ + b] = (float)sLL;
    }
}

// ---------------------------------------------------------------------------
// v7 fallback decoder (round-7 kernel, verbatim): used when ws_size is too
// small for the KK tables. Known-good at ~4080 us.
// ---------------------------------------------------------------------------
__global__ __launch_bounds__(512, 2)
void k_decode_v7(const float* __restrict__ depot_xy,
                 const float* __restrict__ customer_xy,
                 const float* __restrict__ demand,
                 const float* __restrict__ node_emb,
                 const float* __restrict__ graph_emb,
                 const float* __restrict__ Wk1,
                 const float* __restrict__ Wv,
                 const float* __restrict__ Wq_fixed,
                 const float* __restrict__ Wq_step,
                 const double* __restrict__ M64,
                 const float* __restrict__ M32,
                 float* __restrict__ out)
{
    __shared__ float  sKs[NN * E_];
    __shared__ float  sV [NN * E_];
    __shared__ double sU[2224];
    __shared__ double sQfix64[E_];
    __shared__ double sWqD64[E_];
    __shared__ float  sQfix32[E_];
    __shared__ float  sWqD32[E_];
    __shared__ float  sInvS[8];
    __shared__ float  sCoord[2 * NN];
    __shared__ float  sDem[NC];
    __shared__ float  sD;
    __shared__ double sCost, sLL;
    __shared__ float  sPosX, sPosY;
    __shared__ int    sPrev, sMaskDepot, sTrig, sOvf;
    __shared__ unsigned long long sVis0, sVis1;

    float* fSc   = (float*)sU;
    float* fPart = (float*)sU + 832;
    float* fPx   = (float*)sU + 1344;
    double* dUZ = sU;
    double* dSc = sU + 1024;
    double* dQ1 = sU + 1832;
    double* dGl = sU + 1960;
    double* dVg = sU + 2088;

    const int b      = blockIdx.x;
    const int tid    = threadIdx.x;
    const int lane   = tid & 63;
    const int h      = __builtin_amdgcn_readfirstlane(tid >> 6);
    const int k1     = lane + 64;
    const int k_lane = tid & 127;
    const int q2u    = __builtin_amdgcn_readfirstlane(tid >> 7);
    const int e0     = q2u * 32;
    const int kb     = q2u * 26;

    const float* emb = node_emb + (size_t)b * NN * E_;

    if (tid < E_) {
        const float* ge = graph_emb + (size_t)b * E_;
        double acc = 0.0;
        for (int g = 0; g < E_; ++g)
            acc += (double)ge[g] * (double)Wq_fixed[g * E_ + tid];
        sQfix64[tid] = acc;
        sQfix32[tid] = (float)acc;
        sWqD64[tid]  = (double)Wq_step[128 * E_ + tid];
        sWqD32[tid]  = Wq_step[128 * E_ + tid];
    }
    if (tid < 2 * NN) {
        int k = tid >> 1, xy = tid & 1;
        sCoord[tid] = (k == 0) ? depot_xy[(size_t)b * 2 + xy]
                               : customer_xy[((size_t)b * NC + (k - 1)) * 2 + xy];
    }
    if (tid < NC) sDem[tid] = demand[(size_t)b * NC + tid];
    if (tid == 0) {
        sD = 1.f; sPrev = 0; sVis0 = 0ull; sVis1 = 0ull;
        sMaskDepot = 1; sCost = 0.0; sLL = 0.0; sTrig = 0; sOvf = 0;
        sPosX = depot_xy[(size_t)b * 2 + 0];
        sPosY = depot_xy[(size_t)b * 2 + 1];
    }

    for (int idx = tid; idx < NN * 32; idx += 512) {
        int k  = idx >> 5;
        int e4 = (idx & 31) * 4;
        const float* er = emb + (size_t)k * E_;
        float4 aV = {0.f, 0.f, 0.f, 0.f};
        float4 aK = {0.f, 0.f, 0.f, 0.f};
        for (int g = 0; g < E_; ++g) {
            float eg = er[g];
            float4 wv = *(const float4*)(Wv      + (size_t)g * E_ + e4);
            float4 wq = *(const float4*)(Wq_step + (size_t)g * E_ + e4);
            aV.x += eg * wv.x; aV.y += eg * wv.y;
            aV.z += eg * wv.z; aV.w += eg * wv.w;
            aK.x += eg * wq.x; aK.y += eg * wq.y;
            aK.z += eg * wq.z; aK.w += eg * wq.w;
        }
        *(float4*)(sV  + (size_t)k * E_ + e4) = aV;
        *(float4*)(sKs + (size_t)k * E_ + e4) = aK;
    }

    float rA[32];
#pragma unroll
    for (int j = 0; j < 32; ++j) rA[j] = 0.f;
    {
        const float* er0 = emb + (size_t)lane * E_;
        const float* er1 = emb + (size_t)((k1 < NN) ? k1 : lane) * E_;
        const float  e1s = (k1 < NN) ? 1.f : 0.f;
        const float* w1b = Wk1 + h * 16;
        for (int g = 0; g < E_; ++g) {
            float a0 = er0[g];
            float a1 = er1[g] * e1s;
            const float* w1 = w1b + (size_t)g * E_;
#pragma unroll
            for (int d = 0; d < 16; ++d) {
                rA[d]      += a0 * w1[d];
                rA[16 + d] += a1 * w1[d];
            }
        }
    }

    float rK2[32];
#pragma unroll
    for (int j = 0; j < 32; ++j) rK2[j] = 0.f;
    if (k_lane < NN) {
        const float* er = emb + (size_t)k_lane * E_;
        for (int g = 0; g < E_; ++g) {
            float eg = er[g];
            const float* mm = M32 + (size_t)g * E_ + e0;
#pragma unroll
            for (int j = 0; j < 32; ++j) rK2[j] += eg * mm[j];
        }
    }
    __syncthreads();

    for (int t = 0; t < T_; ++t) {
        {
            int prev = sPrev;
            float Dv = sD;
            int d_ = h * 16 + (lane & 15);
            float q1v = (sQfix32[d_] + sKs[(size_t)prev * E_ + d_]
                         + Dv * sWqD32[d_]) * 0.25f;

            unsigned long long v0 = sVis0, v1 = sVis1;
            bool mk0, mk1;
            if (lane == 0) mk0 = (sMaskDepot != 0);
            else {
                int c = lane - 1;
                mk0 = ((v0 >> c) & 1ull) || (sDem[c] > Dv);
            }
            if (k1 < NN) {
                int c = k1 - 1;
                bool vis = (c < 64) ? ((v0 >> c) & 1ull)
                                    : ((v1 >> (c - 64)) & 1ull);
                mk1 = vis || (sDem[c] > Dv);
            } else mk1 = true;

            float s0 = 0.f, s1 = 0.f;
#pragma unroll
            for (int d = 0; d < 16; ++d) {
                float qd = rdlane(q1v, d);
                s0 += rA[d] * qd;
                s1 += rA[16 + d] * qd;
            }
            bool ovf = (!mk0 && s0 > 80.f) || (!mk1 && s1 > 80.f);
            if (__any(ovf)) { if (lane == 0) sOvf = 1; }
            float w0 = mk0 ? 0.f : expf(fminf(s0, 80.f));
            float w1 = mk1 ? 0.f : expf(fminf(s1, 80.f));
            fSc[h * 104 + lane] = w0;
            if (k1 < 104) fSc[h * 104 + k1] = w1;
            float wsum = w0 + w1;
#pragma unroll
            for (int m = 32; m >= 1; m >>= 1) wsum += __shfl_xor(wsum, m);
            if (lane == 0) sInvS[h] = 1.0f / wsum;
        }
        __syncthreads();

        {
            int e = k_lane, hh = e >> 4;
            const float* sc = fSc + hh * 104 + kb;
            const float* vv = sV + (size_t)kb * E_ + e;
            float p = 0.f;
#pragma unroll
            for (int j = 0; j < 26; ++j) p += sc[j] * vv[j * E_];
            fPart[q2u * E_ + e] = p;
        }
        __syncthreads();

        {
            int ee = e0 + (tid & 31);
            float glv = (fPart[ee] + fPart[128 + ee] + fPart[256 + ee]
                         + fPart[384 + ee]) * sInvS[ee >> 4];
            float x = 0.f;
#pragma unroll
            for (int j = 0; j < 32; ++j) x += rK2[j] * rdlane(glv, j);
            if (k_lane < NN) fPx[q2u * E_ + k_lane] = x;
        }
        __syncthreads();

        if (tid < 64) {
            int kA = tid, kB = tid + 64;
            float xA = (fPx[kA] + fPx[128 + kA] + fPx[256 + kA] + fPx[384 + kA]) * INVSQE;
            bool mk1;
            if (kA == 0) mk1 = (sMaskDepot != 0);
            else {
                int c = kA - 1;
                bool vis = (c < 64) ? ((sVis0 >> c) & 1ull) : ((sVis1 >> (c - 64)) & 1ull);
                mk1 = vis || (sDem[c] > sD);
            }
            float xB = -3.0e38f; bool mk2 = true;
            if (kB < NN) {
                xB = (fPx[kB] + fPx[128 + kB] + fPx[256 + kB] + fPx[384 + kB]) * INVSQE;
                int c = kB - 1;
                bool vis = (c < 64) ? ((sVis0 >> c) & 1ull) : ((sVis1 >> (c - 64)) & 1ull);
                mk2 = vis || (sDem[c] > sD);
            }
            float a1v = mk1 ? -3.0e38f : xA;
            float a2v = mk2 ? -3.0e38f : xB;
            float m1, m2; int mi;
            if (a2v > a1v) { m1 = a2v; m2 = a1v; mi = kB; }
            else           { m1 = a1v; m2 = a2v; mi = kA; }
            float ls = 0.f;
            if (!mk1)              ls += expf(10.f * tanhf(xA));
            if (kB < NN && !mk2)   ls += expf(10.f * tanhf(xB));
#pragma unroll
            for (int off = 32; off > 0; off >>= 1) {
                float om1 = __shfl_xor(m1, off);
                float om2 = __shfl_xor(m2, off);
                float os  = __shfl_xor(ls, off);
                int   omi = __shfl_xor(mi, off);
                ls += os;
                if (om1 > m1 || (om1 == m1 && omi < mi)) {
                    m2 = fmaxf(m1, om2); m1 = om1; mi = omi;
                } else {
                    m2 = fmaxf(m2, om1);
                }
            }
            if (tid == 0) {
                float gap = m1 - m2;
                bool trig = !(gap >= GAPTHR) || (sOvf != 0);
                sOvf = 0;
                if (trig) {
                    sTrig = 1;
                } else {
                    float lsel = 10.f * tanhf(m1);
                    float logp = lsel - logf(ls);
                    int nxt = mi;
                    sLL += (double)logp;
                    bool isdep = (nxt == 0);
                    if (isdep) {
                        sD = 1.0f;
                    } else {
                        int c = nxt - 1;
                        sD = sD - sDem[c];
                        if (c < 64) sVis0 |= (1ull << c);
                        else        sVis1 |= (1ull << (c - 64));
                    }
                    bool allv = (sVis0 == 0xFFFFFFFFFFFFFFFFull) &&
                                (sVis1 == 0x0000000FFFFFFFFFull);
                    sMaskDepot = (isdep && !allv) ? 1 : 0;
                    sPrev = nxt;
                    float cx = sCoord[2 * nxt], cy = sCoord[2 * nxt + 1];
                    double dx = (double)cx - (double)sPosX;
                    double dy = (double)cy - (double)sPosY;
                    sCost += sqrt(dx * dx + dy * dy + 1e-10);
                    sPosX = cx; sPosY = cy;
                }
            }
        }
        __syncthreads();

        if (sTrig) {
            if (tid < E_) {
                const float* ep = emb + (size_t)sPrev * E_;
                double ks = 0.0;
                for (int g = 0; g < E_; ++g)
                    ks += (double)ep[g] * (double)Wq_step[(size_t)g * E_ + tid];
                dQ1[tid] = (sQfix64[tid] + ks + (double)sD * sWqD64[tid]) * 0.25;
            }
            __syncthreads();
            for (int idx = tid; idx < 1024; idx += 512) {
                int g = idx >> 3, hh = idx & 7;
                double u = 0.0;
#pragma unroll 4
                for (int d = 0; d < 16; ++d)
                    u += dQ1[hh * 16 + d] * (double)Wk1[(size_t)g * E_ + hh * 16 + d];
                dUZ[idx] = u;
            }
            __syncthreads();
            for (int idx = tid; idx < 1024; idx += 512) {
                int k = idx & 127, hh = idx >> 7;
                if (k < NN) {
                    bool mk;
                    if (k == 0) mk = (sMaskDepot != 0);
                    else {
                        int c = k - 1;
                        bool vis = (c < 64) ? ((sVis0 >> c) & 1ull) : ((sVis1 >> (c - 64)) & 1ull);
                        mk = vis || (sDem[c] > sD);
                    }
                    if (mk) dSc[hh * NN + k] = NEGV;
                    else {
                        const float* ek = emb + (size_t)k * E_;
                        double s = 0.0;
                        for (int g = 0; g < E_; ++g)
                            s += (double)ek[g] * dUZ[g * 8 + hh];
                        dSc[hh * NN + k] = s;
                    }
                }
            }
            __syncthreads();
            {
                int hh = tid >> 6, ln = tid & 63;
                int kA = ln, kB = ln + 64;
                double v1 = dSc[hh * NN + kA];
                double v2 = (kB < NN) ? dSc[hh * NN + kB] : -1.0e300;
                double m = fmax(v1, v2);
#pragma unroll
                for (int off = 32; off > 0; off >>= 1)
                    m = fmax(m, __shfl_xor(m, off));
                double e1 = exp(v1 - m);
                double e2 = (kB < NN) ? exp(v2 - m) : 0.0;
                double s = e1 + e2;
#pragma unroll
                for (int off = 32; off > 0; off >>= 1)
                    s += __shfl_xor(s, off);
                double inv = 1.0 / s;
                dSc[hh * NN + kA] = e1 * inv;
                if (kB < NN) dSc[hh * NN + kB] = e2 * inv;
            }
            __syncthreads();
            for (int idx = tid; idx < 1024; idx += 512) {
                int g = idx >> 3, hh = idx & 7;
                double z = 0.0;
                for (int k = 0; k < NN; ++k)
                    z += dSc[hh * NN + k] * (double)emb[(size_t)k * E_ + g];
                dUZ[idx] = z;
            }
            __syncthreads();
            if (tid < E_) {
                int hh = tid >> 4;
                double g2 = 0.0;
                for (int g = 0; g < E_; ++g)
                    g2 += dUZ[g * 8 + hh] * (double)Wv[(size_t)g * E_ + tid];
                dGl[tid] = g2;
            }
            __syncthreads();
            if (tid < E_) {
                double v = 0.0;
                for (int e = 0; e < E_; ++e)
                    v += dGl[e] * M64[(size_t)tid * E_ + e];
                dVg[tid] = v;
            }
            __syncthreads();
            if (tid < NN) {
                const float* ek = emb + (size_t)tid * E_;
                double x = 0.0;
                for (int g = 0; g < E_; ++g)
                    x += (double)ek[g] * dVg[g];
                dQ1[tid] = x * INVSQED;
            }
            __syncthreads();
            if (tid < 64) {
                int kA = tid, kB = tid + 64;
                double x1 = dQ1[kA];
                bool mk1;
                if (kA == 0) mk1 = (sMaskDepot != 0);
                else {
                    int c = kA - 1;
                    bool vis = (c < 64) ? ((sVis0 >> c) & 1ull) : ((sVis1 >> (c - 64)) & 1ull);
                    mk1 = vis || (sDem[c] > sD);
                }
                double x2 = 0.0; bool mk2 = true;
                if (kB < NN) {
                    x2 = dQ1[kB];
                    int c = kB - 1;
                    bool vis = (c < 64) ? ((sVis0 >> c) & 1ull) : ((sVis1 >> (c - 64)) & 1ull);
                    mk2 = vis || (sDem[c] > sD);
                }
                double a1 = mk1 ? -1.0e300 : x1;
                double a2 = (kB < NN && !mk2) ? x2 : -1.0e300;
                double mv; int mi;
                if (a1 >= a2) { mv = a1; mi = kA; } else { mv = a2; mi = kB; }
#pragma unroll
                for (int off = 32; off > 0; off >>= 1) {
                    double ov = __shfl_xor(mv, off);
                    int    oi = __shfl_xor(mi, off);
                    if (ov > mv || (ov == mv && oi < mi)) { mv = ov; mi = oi; }
                }
                double lmax = 10.0 * tanh(mv);
                double l1 = mk1 ? NEGV : 10.0 * tanh(x1);
                double l2 = (kB < NN) ? (mk2 ? NEGV : 10.0 * tanh(x2)) : 0.0;
                double s = exp(l1 - lmax) + ((kB < NN) ? exp(l2 - lmax) : 0.0);
#pragma unroll
                for (int off = 32; off > 0; off >>= 1)
                    s += __shfl_xor(s, off);
                if (tid == 0) {
                    int nxt = mi;
                    sLL += -log(s);
                    bool isdep = (nxt == 0);
                    if (isdep) {
                        sD = 1.0f;
                    } else {
                        int c = nxt - 1;
                        sD = sD - sDem[c];
                        if (c < 64) sVis0 |= (1ull << c);
                        else        sVis1 |= (1ull << (c - 64));
                    }
                    bool allv = (sVis0 == 0xFFFFFFFFFFFFFFFFull) &&
                                (sVis1 == 0x0000000FFFFFFFFFull);
                    sMaskDepot = (isdep && !allv) ? 1 : 0;
                    sPrev = nxt;
                    float cx = sCoord[2 * nxt], cy = sCoord[2 * nxt + 1];
                    double dx = (double)cx - (double)sPosX;
                    double dy = (double)cy - (double)sPosY;
                    sCost += sqrt(dx * dx + dy * dy + 1e-10);
                    sPosX = cx; sPosY = cy;
                    sTrig = 0;
                }
            }
            __syncthreads();
        }
    }

    if (tid == 0) {
        double dx = (double)sCoord[0] - (double)sPosX;
        double dy = (double)sCoord[1] - (double)sPosY;
        out[b]      = (float)(sCost + sqrt(dx * dx + dy * dy + 1e-10));
        out[B_ + b] = (float)sLL;
    }
}

// ---------------------------------------------------------------------------
extern "C" void kernel_launch(void* const* d_in, const int* in_sizes, int n_in,
                              void* d_out, int out_size, void* d_ws, size_t ws_size,
                              hipStream_t stream) {
    const float* depot = (const float*)d_in[0];
    const float* cust  = (const float*)d_in[1];
    const float* dem   = (const float*)d_in[2];
    const float* nemb  = (const float*)d_in[3];
    const float* gemb  = (const float*)d_in[4];
    const float* Wk1   = (const float*)d_in[5];
    const float* Wv    = (const float*)d_in[6];
    const float* Wk2   = (const float*)d_in[7];
    const float* Wqf   = (const float*)d_in[8];
    const float* Wout  = (const float*)d_in[9];
    const float* Wqs   = (const float*)d_in[10];
    float*  out = (float*)d_out;

    double* M64 = (double*)d_ws;                       // 128 KB @ 0
    float*  M32 = (float*)((char*)d_ws + 131072);      // 64 KB  @ 128K

    const size_t OFF_B0   = 196608;
    const size_t B0_BYTES = (size_t)B_ * 8 * NN * sizeof(float);       // ~3.3 MB
    const size_t OFF_KK   = OFF_B0 + ((B0_BYTES + 255) / 256) * 256;
    const size_t KK_BYTES = (size_t)B_ * 8 * NN * NN * sizeof(float);  // ~334 MB
    const bool   fast     = ws_size >= OFF_KK + KK_BYTES;

    k_weights<<<dim3(128), dim3(128), 0, stream>>>(Wk2, Wout, M64, M32);

    if (fast) {
        float* B0g = (float*)((char*)d_ws + OFF_B0);
        float* KK  = (float*)((char*)d_ws + OFF_KK);
        k_prep<<<dim3(B_), dim3(512), 0, stream>>>(nemb, gemb, Wk1, Wqs, Wqf,
                                                   KK, B0g);
        k_decode_kk<<<dim3(B_), dim3(512), 0, stream>>>(depot, cust, dem, nemb,
                                                        gemb, Wk1, Wv, Wqf, Wqs,
                                                        M64, M32, KK, B0g, out);
    } else {
        k_decode_v7<<<dim3(B_), dim3(512), 0, stream>>>(depot, cust, dem, nemb,
                                                        gemb, Wk1, Wv, Wqf, Wqs,
                                                        M64, M32, out);
    }
}